// Round 6
// baseline (15798.811 us; speedup 1.0000x reference)
//
#include <hip/hip_runtime.h>
#include <hip/hip_bf16.h>
#include <cstdint>
#include <cstddef>

// Problem constants
#define T_STEPS 8192
#define IN_DIM  1024
#define HID     1024
#define OUT_DIM 1024
#define G4      4096   // 4*HID

// Recurrence geometry: 64 blocks x 512 threads = 8 waves/block, 512 waves.
// Each wave owns 2 hidden units (8 W_h rows) in EIGHT NAMED f32x16 vector
// registers (128 VGPRs). R4/R5 showed the compiler REMATERIALIZES these
// (sinks the global loads into the step loop: VGPR_Count=84, 16.7MB/step of
// L3 traffic = the entire 1.67us step time). The empty asm with "+v"
// constraints inside the loop makes the values opaque -- they cannot be
// re-derived by reloading, forcing true VGPR residency for all 8192 steps.
#define NBLK 64
#define TPB  512
#define WPB  8    // waves per block
#define UPW  2    // hidden units per wave

typedef __attribute__((ext_vector_type(16))) float f32x16;

__device__ __forceinline__ float sigf(float x) {
  return 1.0f / (1.0f + __expf(-x));
}

// Halving reduce step: pair (lane, lane^mask); lane with bit==0 ends with
// row-a total partial, bit==1 with row-b.
__device__ __forceinline__ float halvestep(float a, float b, int mask, int lane) {
  float x = (lane & mask) ? a : b;     // what my partner needs
  float y = __shfl_xor(x, mask);
  return ((lane & mask) ? b : a) + y;
}

// ---------------------------------------------------------------------------
// GEMM: C[M,N] = A[M,K] @ B[N,K]^T + bias[N]  (64x64 tile, 256 thr, 4x4 micro)
// ---------------------------------------------------------------------------
__global__ __launch_bounds__(256) void gemm_nt(
    const float* __restrict__ A, int lda,
    const float* __restrict__ B, int ldb,
    const float* __restrict__ bias,
    float* __restrict__ C, int ldc,
    int K)
{
  __shared__ float As[16][72];
  __shared__ float Bs[16][72];

  const int tid = threadIdx.x;
  const int m0 = blockIdx.y * 64;
  const int n0 = blockIdx.x * 64;
  const int lr = tid >> 2;
  const int lk = (tid & 3) * 4;
  const int ty = tid >> 4;
  const int tx = tid & 15;

  float acc[4][4];
#pragma unroll
  for (int i = 0; i < 4; ++i)
#pragma unroll
    for (int j = 0; j < 4; ++j) acc[i][j] = 0.0f;

  const float* Ag = A + (size_t)(m0 + lr) * lda + lk;
  const float* Bg = B + (size_t)(n0 + lr) * ldb + lk;

  for (int kt = 0; kt < K; kt += 16) {
    float4 av = *(const float4*)(Ag + kt);
    float4 bv = *(const float4*)(Bg + kt);
    __syncthreads();
    As[lk + 0][lr] = av.x; As[lk + 1][lr] = av.y;
    As[lk + 2][lr] = av.z; As[lk + 3][lr] = av.w;
    Bs[lk + 0][lr] = bv.x; Bs[lk + 1][lr] = bv.y;
    Bs[lk + 2][lr] = bv.z; Bs[lk + 3][lr] = bv.w;
    __syncthreads();
#pragma unroll
    for (int k = 0; k < 16; ++k) {
      float4 a4 = *(const float4*)&As[k][ty * 4];
      float4 b4 = *(const float4*)&Bs[k][tx * 4];
      acc[0][0] = fmaf(a4.x, b4.x, acc[0][0]); acc[0][1] = fmaf(a4.x, b4.y, acc[0][1]);
      acc[0][2] = fmaf(a4.x, b4.z, acc[0][2]); acc[0][3] = fmaf(a4.x, b4.w, acc[0][3]);
      acc[1][0] = fmaf(a4.y, b4.x, acc[1][0]); acc[1][1] = fmaf(a4.y, b4.y, acc[1][1]);
      acc[1][2] = fmaf(a4.y, b4.z, acc[1][2]); acc[1][3] = fmaf(a4.y, b4.w, acc[1][3]);
      acc[2][0] = fmaf(a4.z, b4.x, acc[2][0]); acc[2][1] = fmaf(a4.z, b4.y, acc[2][1]);
      acc[2][2] = fmaf(a4.z, b4.z, acc[2][2]); acc[2][3] = fmaf(a4.z, b4.w, acc[2][3]);
      acc[3][0] = fmaf(a4.w, b4.x, acc[3][0]); acc[3][1] = fmaf(a4.w, b4.y, acc[3][1]);
      acc[3][2] = fmaf(a4.w, b4.z, acc[3][2]); acc[3][3] = fmaf(a4.w, b4.w, acc[3][3]);
    }
  }

  float4 b4 = *(const float4*)(bias + n0 + tx * 4);
#pragma unroll
  for (int i = 0; i < 4; ++i) {
    float4 o;
    o.x = acc[i][0] + b4.x; o.y = acc[i][1] + b4.y;
    o.z = acc[i][2] + b4.z; o.w = acc[i][3] + b4.w;
    *(float4*)(C + (size_t)(m0 + ty * 4 + i) * ldc + n0 + tx * 4) = o;
  }
}

// ---------------------------------------------------------------------------
// Persistent recurrence: tagged dataflow (no device barrier) + per-block LDS
// staging + asm-pinned register-resident weights.
// hbuf: [2][1024] u64 {lo=tag, hi=float bits}. Step t: wave j polls its
// 128-elem slice of slot t&1 for tag t -> LDS -> __syncthreads -> full h.
// Row m = ul*4+g of this wave's 8 W_h rows; after the halving reduce, lane l
// holds row (l&7)'s sum. Lane-distributed activations, quad-shuffle gather
// for the c/h update; lanes 0 and 4 publish h for units u0, u0+1.
// ---------------------------------------------------------------------------
__global__ __launch_bounds__(TPB, 1) void lstm_rec(
    const float* __restrict__ Ww,                 // [4096, 2048]
    const float* __restrict__ pre,                // [T, 4096]
    unsigned long long* __restrict__ hbuf,        // [2][1024] tagged
    float* __restrict__ hall)                     // [T, 1024]
{
  __shared__ float lh[2][HID];

  const int lane = threadIdx.x & 63;
  const int wslot = threadIdx.x >> 6;                 // 0..7
  const int wv = blockIdx.x * WPB + wslot;            // 0..511
  const int u0 = wv * UPW;

  // Per-lane gate/unit identity for the post-reduce phase (replicated mod 8)
  const int g  = lane & 3;          // 0:i 1:f 2:g 3:o
  const int ul = (lane >> 2) & 1;   // unit within wave
  const size_t preoff = (size_t)g * HID + u0 + ul;

  // Persistent weights in named vector registers. Row m = ul*4+g.
  // Lane's e-slice: e = q*64 + lane (matches LDS h layout).
  auto loadrow = [&](int gg, int uu) {
    const float* wr = Ww + (size_t)(gg * HID + u0 + uu) * (IN_DIM + HID) + IN_DIM;
    f32x16 v;
#pragma unroll
    for (int q = 0; q < 16; ++q) v[q] = wr[q * 64 + lane];
    return v;
  };
  f32x16 w0 = loadrow(0, 0), w1 = loadrow(1, 0), w2 = loadrow(2, 0), w3 = loadrow(3, 0);
  f32x16 w4 = loadrow(0, 1), w5 = loadrow(1, 1), w6 = loadrow(2, 1), w7 = loadrow(3, 1);

  float c = 0.0f;                      // cell state, replicated per quad
  float pv = pre[preoff];              // pre-gate for step 0 (pipelined)

  for (int t = 0; t < T_STEPS; ++t) {
    // Opaque-value barrier: outputs of this asm cannot be rematerialized by
    // reloading from memory, so w0..w7 MUST live in VGPRs across iterations.
    asm volatile("" : "+v"(w0), "+v"(w1), "+v"(w2), "+v"(w3),
                      "+v"(w4), "+v"(w5), "+v"(w6), "+v"(w7));

    // issue next step's pre load now -- a full step of latency cover
    const int tn = (t + 1 < T_STEPS) ? (t + 1) : t;
    const float pv_next = pre[(size_t)tn * G4 + preoff];

    // Poll my 128-element slice of h_{t-1} (2 tagged u64 loads/lane)
    const unsigned long long* hs = hbuf + (size_t)(t & 1) * HID + wslot * 128;
    const unsigned want = (unsigned)t;
    unsigned long long p0, p1;
    for (;;) {
      p0 = __hip_atomic_load(hs + lane, __ATOMIC_RELAXED, __HIP_MEMORY_SCOPE_AGENT);
      p1 = __hip_atomic_load(hs + 64 + lane, __ATOMIC_RELAXED, __HIP_MEMORY_SCOPE_AGENT);
      bool ok = ((unsigned)p0 == want) & ((unsigned)p1 == want);
      if (__all((int)ok)) break;
    }
    lh[t & 1][wslot * 128 + lane]      = __uint_as_float((unsigned)(p0 >> 32));
    lh[t & 1][wslot * 128 + 64 + lane] = __uint_as_float((unsigned)(p1 >> 32));
    __syncthreads();

    // Full h from LDS (bank = lane%32, 2 lanes/bank: free)
    float hv[16];
#pragma unroll
    for (int q = 0; q < 16; ++q) hv[q] = lh[t & 1][q * 64 + lane];

    // matvec: 8 rows x 16 elems, weights in VGPRs
    float a0 = 0, a1 = 0, a2 = 0, a3 = 0, a4 = 0, a5 = 0, a6 = 0, a7 = 0;
#pragma unroll
    for (int q = 0; q < 16; ++q) {
      const float h = hv[q];
      a0 = fmaf(w0[q], h, a0); a1 = fmaf(w1[q], h, a1);
      a2 = fmaf(w2[q], h, a2); a3 = fmaf(w3[q], h, a3);
      a4 = fmaf(w4[q], h, a4); a5 = fmaf(w5[q], h, a5);
      a6 = fmaf(w6[q], h, a6); a7 = fmaf(w7[q], h, a7);
    }

    // Halving reduce: 7 shuffles to land row (lane&7) in lane, then 3 full
    // butterflies over the remaining lane bits.
    float r0 = halvestep(a0, a1, 1, lane);
    float r1 = halvestep(a2, a3, 1, lane);
    float r2 = halvestep(a4, a5, 1, lane);
    float r3 = halvestep(a6, a7, 1, lane);
    float s0 = halvestep(r0, r1, 2, lane);
    float s1 = halvestep(r2, r3, 2, lane);
    float u  = halvestep(s0, s1, 4, lane);
    u += __shfl_xor(u, 8); u += __shfl_xor(u, 16); u += __shfl_xor(u, 32);
    // lane l now holds the full sum for row m = l&7 (gate g=m&3, unit m>>2)

    const float gv = u + pv;
    // gate activation: sigmoid for i,f,o; tanh for g via 2*sig(2x)-1
    const bool isg = (g == 2);
    const float s = sigf(isg ? 2.0f * gv : gv);
    const float act = isg ? fmaf(2.0f, s, -1.0f) : s;

    // gather my quad's four gate activations
    const int base = lane & ~3;
    const float si = __shfl(act, base);
    const float sf = __shfl(act, base | 1);
    const float tg = __shfl(act, base | 2);
    const float so = __shfl(act, base | 3);

    c = fmaf(sf, c, si * tg);
    const float s2 = sigf(2.0f * c);
    const float h = so * fmaf(2.0f, s2, -1.0f);   // so * tanh(c)

    if (lane < 8 && (lane & 3) == 0) {
      const int unit = u0 + (lane >> 2);
      unsigned long long pk =
          ((unsigned long long)__float_as_uint(h) << 32) | (unsigned)(t + 1);
      __hip_atomic_store(hbuf + (size_t)((t + 1) & 1) * HID + unit, pk,
                         __ATOMIC_RELAXED, __HIP_MEMORY_SCOPE_AGENT);
      hall[(size_t)t * HID + unit] = h;
    }

    pv = pv_next;
  }
}

// ---------------------------------------------------------------------------
// Workspace layout (bytes):
//   [0, 16K)              : hbuf[2][1024] tagged u64  (memset 0: tag0/h=0)
//   [16K, 16K+33.5MB)     : hall[T][1024]
//   [16K+33.5MB, +134MB)  : pre[T][4096]
// ---------------------------------------------------------------------------
extern "C" void kernel_launch(void* const* d_in, const int* in_sizes, int n_in,
                              void* d_out, int out_size, void* d_ws, size_t ws_size,
                              hipStream_t stream) {
  (void)in_sizes; (void)n_in; (void)out_size; (void)ws_size;

  const float* x     = (const float*)d_in[0];  // [T,1,IN]
  const float* W_w   = (const float*)d_in[1];  // [4096, 2048]
  const float* W_b   = (const float*)d_in[2];  // [4096]
  const float* out_w = (const float*)d_in[3];  // [1024, 1024]
  const float* out_b = (const float*)d_in[4];  // [1024]
  float* out = (float*)d_out;                  // [T,1,1024]

  char* ws = (char*)d_ws;
  unsigned long long* hbuf = (unsigned long long*)ws;
  float* hall = (float*)(ws + 16384);
  float* pre  = (float*)(ws + 16384 + (size_t)T_STEPS * HID * 4);

  hipMemsetAsync(ws, 0, 16384, stream);

  // pre = x @ Wx^T + W_b   (Wx = W_w[:, :1024], row stride 2048)
  gemm_nt<<<dim3(G4 / 64, T_STEPS / 64), 256, 0, stream>>>(
      x, IN_DIM, W_w, IN_DIM + HID, W_b, pre, G4, IN_DIM);

  // sequential recurrence, no barrier, block-level h staging
  lstm_rec<<<NBLK, TPB, 0, stream>>>(W_w, pre, hbuf, hall);

  // y = hall @ out_w^T + out_b
  gemm_nt<<<dim3(OUT_DIM / 64, T_STEPS / 64), 256, 0, stream>>>(
      hall, HID, out_w, OUT_DIM, out_b, out, OUT_DIM, HID);
}

// Round 7
// 15498.987 us; speedup vs baseline: 1.0193x; 1.0193x over previous
//
#include <hip/hip_runtime.h>
#include <hip/hip_bf16.h>
#include <cstdint>
#include <cstddef>

// Problem constants
#define T_STEPS 8192
#define IN_DIM  1024
#define HID     1024
#define OUT_DIM 1024
#define G4      4096   // 4*HID

// Recurrence geometry: 256 blocks x 256 threads (4 waves), 1 block/CU.
// Each block owns 4 hidden units = 16 W_h rows staged ONCE into LDS (64 KB).
// Each wave computes 1 unit (4 gate rows). R3-R6 showed the register
// allocator refuses to keep 128 persistent weight VGPRs (VGPR_Count pinned
// at 84, weights re-fetched from cache every step = the whole step time);
// LDS placement is deterministic and its BW (128 B/cy/CU) prices the step
// at ~650 cy instead of ~4250.
#define NBLK 256
#define TPB  256
#define WPB  4    // waves per block
#define UPB  4    // units per block (1 per wave)

__device__ __forceinline__ float sigf(float x) {
  return 1.0f / (1.0f + __expf(-x));
}

// Halving reduce step: pair (lane, lane^mask); lane with bit==0 ends with
// row-a total partial, bit==1 with row-b.
__device__ __forceinline__ float halvestep(float a, float b, int mask, int lane) {
  float x = (lane & mask) ? a : b;     // what my partner needs
  float y = __shfl_xor(x, mask);
  return ((lane & mask) ? b : a) + y;
}

// ---------------------------------------------------------------------------
// GEMM: C[M,N] = A[M,K] @ B[N,K]^T + bias[N]  (64x64 tile, 256 thr, 4x4 micro)
// ---------------------------------------------------------------------------
__global__ __launch_bounds__(256) void gemm_nt(
    const float* __restrict__ A, int lda,
    const float* __restrict__ B, int ldb,
    const float* __restrict__ bias,
    float* __restrict__ C, int ldc,
    int K)
{
  __shared__ float As[16][72];
  __shared__ float Bs[16][72];

  const int tid = threadIdx.x;
  const int m0 = blockIdx.y * 64;
  const int n0 = blockIdx.x * 64;
  const int lr = tid >> 2;
  const int lk = (tid & 3) * 4;
  const int ty = tid >> 4;
  const int tx = tid & 15;

  float acc[4][4];
#pragma unroll
  for (int i = 0; i < 4; ++i)
#pragma unroll
    for (int j = 0; j < 4; ++j) acc[i][j] = 0.0f;

  const float* Ag = A + (size_t)(m0 + lr) * lda + lk;
  const float* Bg = B + (size_t)(n0 + lr) * ldb + lk;

  for (int kt = 0; kt < K; kt += 16) {
    float4 av = *(const float4*)(Ag + kt);
    float4 bv = *(const float4*)(Bg + kt);
    __syncthreads();
    As[lk + 0][lr] = av.x; As[lk + 1][lr] = av.y;
    As[lk + 2][lr] = av.z; As[lk + 3][lr] = av.w;
    Bs[lk + 0][lr] = bv.x; Bs[lk + 1][lr] = bv.y;
    Bs[lk + 2][lr] = bv.z; Bs[lk + 3][lr] = bv.w;
    __syncthreads();
#pragma unroll
    for (int k = 0; k < 16; ++k) {
      float4 a4 = *(const float4*)&As[k][ty * 4];
      float4 b4 = *(const float4*)&Bs[k][tx * 4];
      acc[0][0] = fmaf(a4.x, b4.x, acc[0][0]); acc[0][1] = fmaf(a4.x, b4.y, acc[0][1]);
      acc[0][2] = fmaf(a4.x, b4.z, acc[0][2]); acc[0][3] = fmaf(a4.x, b4.w, acc[0][3]);
      acc[1][0] = fmaf(a4.y, b4.x, acc[1][0]); acc[1][1] = fmaf(a4.y, b4.y, acc[1][1]);
      acc[1][2] = fmaf(a4.y, b4.z, acc[1][2]); acc[1][3] = fmaf(a4.y, b4.w, acc[1][3]);
      acc[2][0] = fmaf(a4.z, b4.x, acc[2][0]); acc[2][1] = fmaf(a4.z, b4.y, acc[2][1]);
      acc[2][2] = fmaf(a4.z, b4.z, acc[2][2]); acc[2][3] = fmaf(a4.z, b4.w, acc[2][3]);
      acc[3][0] = fmaf(a4.w, b4.x, acc[3][0]); acc[3][1] = fmaf(a4.w, b4.y, acc[3][1]);
      acc[3][2] = fmaf(a4.w, b4.z, acc[3][2]); acc[3][3] = fmaf(a4.w, b4.w, acc[3][3]);
    }
  }

  float4 b4 = *(const float4*)(bias + n0 + tx * 4);
#pragma unroll
  for (int i = 0; i < 4; ++i) {
    float4 o;
    o.x = acc[i][0] + b4.x; o.y = acc[i][1] + b4.y;
    o.z = acc[i][2] + b4.z; o.w = acc[i][3] + b4.w;
    *(float4*)(C + (size_t)(m0 + ty * 4 + i) * ldc + n0 + tx * 4) = o;
  }
}

// ---------------------------------------------------------------------------
// Persistent recurrence: tagged dataflow (no device barrier) + LDS-resident
// weights + per-block LDS h staging.
// hbuf: [2][1024] u64 {lo=tag, hi=float bits}. Step t: wave j polls its
// 256-elem chunk of slot t&1 for tag t (4 u64/lane) -> deposits values into
// lh[t&1] -> __syncthreads -> all waves read full h + their weight rows from
// LDS -> 4 row-dots -> 7-shuffle halving reduce (lane l holds gate l&3) ->
// lane-distributed activations -> quad gather -> c,h update -> lane 0
// publishes unit u = blockIdx*4 + wslot with tag t+1.
// Skew safety: every block consumes the FULL h each step, so a tag t+2 store
// implies all blocks passed poll t+1 -> depth-2 slots never skip a tag.
// Intra-block: single barrier + parity-indexed lh slots are race-free.
// ---------------------------------------------------------------------------
__global__ __launch_bounds__(TPB, 1) void lstm_rec(
    const float* __restrict__ Ww,                 // [4096, 2048]
    const float* __restrict__ pre,                // [T, 4096]
    unsigned long long* __restrict__ hbuf,        // [2][1024] tagged
    float* __restrict__ hall)                     // [T, 1024]
{
  __shared__ float wlds[16][HID];   // 64 KB: rows m = ul*4+g for this block
  __shared__ float lh[2][HID];      // 8 KB: staged h, double-buffered

  const int tid = threadIdx.x;
  const int lane = tid & 63;
  const int wslot = tid >> 6;                 // 0..3 = unit-in-block
  const int u = blockIdx.x * UPB + wslot;     // this wave's hidden unit

  // Stage the block's 16 weight rows into LDS (float4, coalesced).
  {
    const float4* __restrict__ Ww4 = (const float4*)Ww;  // row stride 512 f4
    float4* w4 = (float4*)&wlds[0][0];
    for (int i = tid; i < 16 * (HID / 4); i += TPB) {
      const int m = i >> 8;            // 0..15
      const int e4 = i & 255;          // float4 index within row
      const int gg = m & 3;
      const int ul = m >> 2;
      w4[i] = Ww4[(size_t)(gg * HID + blockIdx.x * UPB + ul) * 512 + (IN_DIM / 4) + e4];
    }
  }
  __syncthreads();

  // Per-lane gate identity (replicated x16 across the wave)
  const int g = lane & 3;            // 0:i 1:f 2:g 3:o
  const size_t preoff = (size_t)g * HID + u;

  const float4* wl4 = (const float4*)&wlds[wslot * 4][0];  // row r at +r*256

  float c = 0.0f;
  float pv = pre[preoff];            // pre-gate for step 0 (pipelined)

  for (int t = 0; t < T_STEPS; ++t) {
    // next step's pre load -- a full step of latency cover
    const int tn = (t + 1 < T_STEPS) ? (t + 1) : t;
    const float pv_next = pre[(size_t)tn * G4 + preoff];

    // Poll my wave's 256-elem chunk of h_{t-1} (4 tagged u64 loads/lane)
    const unsigned long long* hs = hbuf + (size_t)(t & 1) * HID + wslot * 256;
    const unsigned want = (unsigned)t;
    unsigned long long p0, p1, p2, p3;
    for (;;) {
      p0 = __hip_atomic_load(hs + lane,       __ATOMIC_RELAXED, __HIP_MEMORY_SCOPE_AGENT);
      p1 = __hip_atomic_load(hs + 64 + lane,  __ATOMIC_RELAXED, __HIP_MEMORY_SCOPE_AGENT);
      p2 = __hip_atomic_load(hs + 128 + lane, __ATOMIC_RELAXED, __HIP_MEMORY_SCOPE_AGENT);
      p3 = __hip_atomic_load(hs + 192 + lane, __ATOMIC_RELAXED, __HIP_MEMORY_SCOPE_AGENT);
      bool ok = ((unsigned)p0 == want) & ((unsigned)p1 == want) &
                ((unsigned)p2 == want) & ((unsigned)p3 == want);
      if (__all((int)ok)) break;
    }
    float* dst = &lh[t & 1][wslot * 256];
    dst[lane]       = __uint_as_float((unsigned)(p0 >> 32));
    dst[64 + lane]  = __uint_as_float((unsigned)(p1 >> 32));
    dst[128 + lane] = __uint_as_float((unsigned)(p2 >> 32));
    dst[192 + lane] = __uint_as_float((unsigned)(p3 >> 32));
    __syncthreads();

    // Full h from LDS: 4 x ds_read_b128, elems e = q*256 + lane*4 + 0..3
    const float4* lhp = (const float4*)&lh[t & 1][0];
    float4 hv0 = lhp[lane];
    float4 hv1 = lhp[64 + lane];
    float4 hv2 = lhp[128 + lane];
    float4 hv3 = lhp[192 + lane];

    // 4 gate-row dots: weights from LDS (16 x ds_read_b128/lane)
    float a0 = 0, a1 = 0, a2 = 0, a3 = 0;
#pragma unroll
    for (int r = 0; r < 4; ++r) {
      const float4 w0 = wl4[r * 256 + lane];
      const float4 w1 = wl4[r * 256 + 64 + lane];
      const float4 w2 = wl4[r * 256 + 128 + lane];
      const float4 w3 = wl4[r * 256 + 192 + lane];
      float a = 0.0f;
      a = fmaf(w0.x, hv0.x, a); a = fmaf(w0.y, hv0.y, a);
      a = fmaf(w0.z, hv0.z, a); a = fmaf(w0.w, hv0.w, a);
      a = fmaf(w1.x, hv1.x, a); a = fmaf(w1.y, hv1.y, a);
      a = fmaf(w1.z, hv1.z, a); a = fmaf(w1.w, hv1.w, a);
      a = fmaf(w2.x, hv2.x, a); a = fmaf(w2.y, hv2.y, a);
      a = fmaf(w2.z, hv2.z, a); a = fmaf(w2.w, hv2.w, a);
      a = fmaf(w3.x, hv3.x, a); a = fmaf(w3.y, hv3.y, a);
      a = fmaf(w3.z, hv3.z, a); a = fmaf(w3.w, hv3.w, a);
      if (r == 0) a0 = a; else if (r == 1) a1 = a;
      else if (r == 2) a2 = a; else a3 = a;
    }

    // Halving reduce: 3 shuffles land gate (lane&3) in lane; 4 butterflies
    // sum across the 16 remaining lane-groups.
    float r0 = halvestep(a0, a1, 1, lane);
    float r1 = halvestep(a2, a3, 1, lane);
    float s  = halvestep(r0, r1, 2, lane);
    s += __shfl_xor(s, 4); s += __shfl_xor(s, 8);
    s += __shfl_xor(s, 16); s += __shfl_xor(s, 32);
    // lane l holds the full pre-activation sum for gate l&3

    const float gv = s + pv;
    // sigmoid for i,f,o; tanh for g via 2*sig(2x)-1
    const bool isg = (g == 2);
    const float sg = sigf(isg ? 2.0f * gv : gv);
    const float act = isg ? fmaf(2.0f, sg, -1.0f) : sg;

    // gather my quad's four gate activations
    const int base = lane & ~3;
    const float si = __shfl(act, base);
    const float sf = __shfl(act, base | 1);
    const float tg = __shfl(act, base | 2);
    const float so = __shfl(act, base | 3);

    c = fmaf(sf, c, si * tg);
    const float s2 = sigf(2.0f * c);
    const float h = so * fmaf(2.0f, s2, -1.0f);   // so * tanh(c)

    if (lane == 0) {
      unsigned long long pk =
          ((unsigned long long)__float_as_uint(h) << 32) | (unsigned)(t + 1);
      __hip_atomic_store(hbuf + (size_t)((t + 1) & 1) * HID + u, pk,
                         __ATOMIC_RELAXED, __HIP_MEMORY_SCOPE_AGENT);
      hall[(size_t)t * HID + u] = h;
    }

    pv = pv_next;
  }
}

// ---------------------------------------------------------------------------
// Workspace layout (bytes):
//   [0, 16K)              : hbuf[2][1024] tagged u64  (memset 0: tag0/h=0)
//   [16K, 16K+33.5MB)     : hall[T][1024]
//   [16K+33.5MB, +134MB)  : pre[T][4096]
// ---------------------------------------------------------------------------
extern "C" void kernel_launch(void* const* d_in, const int* in_sizes, int n_in,
                              void* d_out, int out_size, void* d_ws, size_t ws_size,
                              hipStream_t stream) {
  (void)in_sizes; (void)n_in; (void)out_size; (void)ws_size;

  const float* x     = (const float*)d_in[0];  // [T,1,IN]
  const float* W_w   = (const float*)d_in[1];  // [4096, 2048]
  const float* W_b   = (const float*)d_in[2];  // [4096]
  const float* out_w = (const float*)d_in[3];  // [1024, 1024]
  const float* out_b = (const float*)d_in[4];  // [1024]
  float* out = (float*)d_out;                  // [T,1,1024]

  char* ws = (char*)d_ws;
  unsigned long long* hbuf = (unsigned long long*)ws;
  float* hall = (float*)(ws + 16384);
  float* pre  = (float*)(ws + 16384 + (size_t)T_STEPS * HID * 4);

  hipMemsetAsync(ws, 0, 16384, stream);

  // pre = x @ Wx^T + W_b   (Wx = W_w[:, :1024], row stride 2048)
  gemm_nt<<<dim3(G4 / 64, T_STEPS / 64), 256, 0, stream>>>(
      x, IN_DIM, W_w, IN_DIM + HID, W_b, pre, G4, IN_DIM);

  // sequential recurrence: 256 blocks (1/CU), LDS-resident weights
  lstm_rec<<<NBLK, TPB, 0, stream>>>(W_w, pre, hbuf, hall);

  // y = hall @ out_w^T + out_b
  gemm_nt<<<dim3(OUT_DIM / 64, T_STEPS / 64), 256, 0, stream>>>(
      hall, HID, out_w, OUT_DIM, out_b, out, OUT_DIM, HID);
}

// Round 8
// 14643.921 us; speedup vs baseline: 1.0789x; 1.0584x over previous
//
#include <hip/hip_runtime.h>
#include <hip/hip_bf16.h>
#include <cstdint>
#include <cstddef>

// Problem constants
#define T_STEPS 8192
#define IN_DIM  1024
#define HID     1024
#define OUT_DIM 1024
#define G4      4096   // 4*HID

// Recurrence geometry: 256 blocks x 256 threads (4 waves), 1 block/CU.
// Each block owns 4 hidden units = 16 W_h rows staged once into LDS (64 KB).
// R8: the step loop overlaps the LDS weight reads and the HBM pre-prefetch
// with the tag-poll, and uses a RAW barrier (s_waitcnt lgkmcnt(0); s_barrier)
// instead of __syncthreads -- __syncthreads drains vmcnt(0), which was
// serializing the pre load + publish store into every step (R7: 1.75us/step).
#define NBLK 256
#define TPB  256
#define WPB  4    // waves per block
#define UPB  4    // units per block (1 per wave)

typedef __attribute__((ext_vector_type(4))) float f32x4;

__device__ __forceinline__ float sigf(float x) {
  return 1.0f / (1.0f + __expf(-x));
}

// Halving reduce step: pair (lane, lane^mask); lane with bit==0 ends with
// row-a total partial, bit==1 with row-b.
__device__ __forceinline__ float halvestep(float a, float b, int mask, int lane) {
  float x = (lane & mask) ? a : b;     // what my partner needs
  float y = __shfl_xor(x, mask);
  return ((lane & mask) ? b : a) + y;
}

// ---------------------------------------------------------------------------
// GEMM: C[M,N] = A[M,K] @ B[N,K]^T + bias[N]  (64x64 tile, 256 thr, 4x4 micro)
// ---------------------------------------------------------------------------
__global__ __launch_bounds__(256) void gemm_nt(
    const float* __restrict__ A, int lda,
    const float* __restrict__ B, int ldb,
    const float* __restrict__ bias,
    float* __restrict__ C, int ldc,
    int K)
{
  __shared__ float As[16][72];
  __shared__ float Bs[16][72];

  const int tid = threadIdx.x;
  const int m0 = blockIdx.y * 64;
  const int n0 = blockIdx.x * 64;
  const int lr = tid >> 2;
  const int lk = (tid & 3) * 4;
  const int ty = tid >> 4;
  const int tx = tid & 15;

  float acc[4][4];
#pragma unroll
  for (int i = 0; i < 4; ++i)
#pragma unroll
    for (int j = 0; j < 4; ++j) acc[i][j] = 0.0f;

  const float* Ag = A + (size_t)(m0 + lr) * lda + lk;
  const float* Bg = B + (size_t)(n0 + lr) * ldb + lk;

  for (int kt = 0; kt < K; kt += 16) {
    float4 av = *(const float4*)(Ag + kt);
    float4 bv = *(const float4*)(Bg + kt);
    __syncthreads();
    As[lk + 0][lr] = av.x; As[lk + 1][lr] = av.y;
    As[lk + 2][lr] = av.z; As[lk + 3][lr] = av.w;
    Bs[lk + 0][lr] = bv.x; Bs[lk + 1][lr] = bv.y;
    Bs[lk + 2][lr] = bv.z; Bs[lk + 3][lr] = bv.w;
    __syncthreads();
#pragma unroll
    for (int k = 0; k < 16; ++k) {
      float4 a4 = *(const float4*)&As[k][ty * 4];
      float4 b4 = *(const float4*)&Bs[k][tx * 4];
      acc[0][0] = fmaf(a4.x, b4.x, acc[0][0]); acc[0][1] = fmaf(a4.x, b4.y, acc[0][1]);
      acc[0][2] = fmaf(a4.x, b4.z, acc[0][2]); acc[0][3] = fmaf(a4.x, b4.w, acc[0][3]);
      acc[1][0] = fmaf(a4.y, b4.x, acc[1][0]); acc[1][1] = fmaf(a4.y, b4.y, acc[1][1]);
      acc[1][2] = fmaf(a4.y, b4.z, acc[1][2]); acc[1][3] = fmaf(a4.y, b4.w, acc[1][3]);
      acc[2][0] = fmaf(a4.z, b4.x, acc[2][0]); acc[2][1] = fmaf(a4.z, b4.y, acc[2][1]);
      acc[2][2] = fmaf(a4.z, b4.z, acc[2][2]); acc[2][3] = fmaf(a4.z, b4.w, acc[2][3]);
      acc[3][0] = fmaf(a4.w, b4.x, acc[3][0]); acc[3][1] = fmaf(a4.w, b4.y, acc[3][1]);
      acc[3][2] = fmaf(a4.w, b4.z, acc[3][2]); acc[3][3] = fmaf(a4.w, b4.w, acc[3][3]);
    }
  }

  float4 b4 = *(const float4*)(bias + n0 + tx * 4);
#pragma unroll
  for (int i = 0; i < 4; ++i) {
    float4 o;
    o.x = acc[i][0] + b4.x; o.y = acc[i][1] + b4.y;
    o.z = acc[i][2] + b4.z; o.w = acc[i][3] + b4.w;
    *(float4*)(C + (size_t)(m0 + ty * 4 + i) * ldc + n0 + tx * 4) = o;
  }
}

// ---------------------------------------------------------------------------
// Persistent recurrence: tagged dataflow (no device barrier) + LDS-resident
// weights, poll-overlapped weight reads, raw LDS-only barrier.
// hbuf: [2][1024] u64 {lo=tag, hi=float bits}. Step t per wave:
//   A) issue 16 ds_read_b128 of my 4 weight rows into regs (static data)
//   B) issue pre[t+1] prefetch (stays in flight across the raw barrier)
//   C) poll my 256-elem chunk of slot t&1 for tag t; deposit into lh[t&1]
//   D) s_waitcnt lgkmcnt(0); s_barrier   (vmem NOT drained)
//   E) read full h from LDS, 64 FMAs vs reg-held weights, 7-stage reduce,
//      activations, lane 0 publishes unit u with tag t+1 (fire-and-forget).
// Skew safety: every block consumes the FULL h each step -> tag t+2 store
// implies all blocks passed poll t+1 -> depth-2 slots never skip a tag.
// Publish stores are never vmcnt-drained in-loop; pollers block until they
// land, so visibility is enforced by the consumers.
// ---------------------------------------------------------------------------
__global__ __launch_bounds__(TPB, 1) void lstm_rec(
    const float* __restrict__ Ww,                 // [4096, 2048]
    const float* __restrict__ pre,                // [T, 4096]
    unsigned long long* __restrict__ hbuf,        // [2][1024] tagged
    float* __restrict__ hall)                     // [T, 1024]
{
  __shared__ float wlds[16][HID];   // 64 KB: rows m = ul*4+g for this block
  __shared__ float lh[2][HID];      // 8 KB: staged h, double-buffered

  const int tid = threadIdx.x;
  const int lane = tid & 63;
  const int wslot = tid >> 6;                 // 0..3 = unit-in-block
  const int u = blockIdx.x * UPB + wslot;     // this wave's hidden unit

  // Stage the block's 16 weight rows into LDS (float4, coalesced).
  {
    const float4* __restrict__ Ww4 = (const float4*)Ww;  // row stride 512 f4
    float4* w4 = (float4*)&wlds[0][0];
    for (int i = tid; i < 16 * (HID / 4); i += TPB) {
      const int m = i >> 8;            // 0..15
      const int e4 = i & 255;          // float4 index within row
      const int gg = m & 3;
      const int ul = m >> 2;
      w4[i] = Ww4[(size_t)(gg * HID + blockIdx.x * UPB + ul) * 512 + (IN_DIM / 4) + e4];
    }
  }
  __syncthreads();

  // Per-lane gate identity (replicated x16 across the wave)
  const int g = lane & 3;            // 0:i 1:f 2:g 3:o
  const size_t preoff = (size_t)g * HID + u;

  const f32x4* wl4 = (const f32x4*)&wlds[wslot * 4][0];  // row r at +r*256
  const f32x4* lh0 = (const f32x4*)&lh[0][0];
  const f32x4* lh1 = (const f32x4*)&lh[1][0];

  float c = 0.0f;
  float pv = pre[preoff];            // pre-gate for step 0 (pipelined)

  for (int t = 0; t < T_STEPS; ++t) {
    // A) weight reads first: latency hides under the poll. Pin to regs.
    f32x4 W0  = wl4[0 * 256 + lane],       W1  = wl4[0 * 256 + 64 + lane],
          W2  = wl4[0 * 256 + 128 + lane], W3  = wl4[0 * 256 + 192 + lane];
    f32x4 W4  = wl4[1 * 256 + lane],       W5  = wl4[1 * 256 + 64 + lane],
          W6  = wl4[1 * 256 + 128 + lane], W7  = wl4[1 * 256 + 192 + lane];
    f32x4 W8  = wl4[2 * 256 + lane],       W9  = wl4[2 * 256 + 64 + lane],
          W10 = wl4[2 * 256 + 128 + lane], W11 = wl4[2 * 256 + 192 + lane];
    f32x4 W12 = wl4[3 * 256 + lane],       W13 = wl4[3 * 256 + 64 + lane],
          W14 = wl4[3 * 256 + 128 + lane], W15 = wl4[3 * 256 + 192 + lane];
    asm volatile("" : "+v"(W0), "+v"(W1), "+v"(W2), "+v"(W3),
                      "+v"(W4), "+v"(W5), "+v"(W6), "+v"(W7),
                      "+v"(W8), "+v"(W9), "+v"(W10), "+v"(W11),
                      "+v"(W12), "+v"(W13), "+v"(W14), "+v"(W15));

    // B) next step's pre load -- full-step latency cover (never drained)
    const int tn = (t + 1 < T_STEPS) ? (t + 1) : t;
    const float pv_next = pre[(size_t)tn * G4 + preoff];

    // C) Poll my wave's 256-elem chunk of h_{t-1} (4 tagged u64 loads/lane)
    const unsigned long long* hs = hbuf + (size_t)(t & 1) * HID + wslot * 256;
    const unsigned want = (unsigned)t;
    unsigned long long p0, p1, p2, p3;
    for (;;) {
      p0 = __hip_atomic_load(hs + lane,       __ATOMIC_RELAXED, __HIP_MEMORY_SCOPE_AGENT);
      p1 = __hip_atomic_load(hs + 64 + lane,  __ATOMIC_RELAXED, __HIP_MEMORY_SCOPE_AGENT);
      p2 = __hip_atomic_load(hs + 128 + lane, __ATOMIC_RELAXED, __HIP_MEMORY_SCOPE_AGENT);
      p3 = __hip_atomic_load(hs + 192 + lane, __ATOMIC_RELAXED, __HIP_MEMORY_SCOPE_AGENT);
      bool ok = ((unsigned)p0 == want) & ((unsigned)p1 == want) &
                ((unsigned)p2 == want) & ((unsigned)p3 == want);
      if (__all((int)ok)) break;
    }
    float* dst = &lh[t & 1][wslot * 256];
    dst[lane]       = __uint_as_float((unsigned)(p0 >> 32));
    dst[64 + lane]  = __uint_as_float((unsigned)(p1 >> 32));
    dst[128 + lane] = __uint_as_float((unsigned)(p2 >> 32));
    dst[192 + lane] = __uint_as_float((unsigned)(p3 >> 32));

    // D) raw barrier: drain LDS ops only; global loads/stores stay in flight
    asm volatile("s_waitcnt lgkmcnt(0)\n\ts_barrier" ::: "memory");

    // E) full h from LDS: 4 x ds_read_b128
    const f32x4* lhp = (t & 1) ? lh1 : lh0;
    f32x4 hv0 = lhp[lane];
    f32x4 hv1 = lhp[64 + lane];
    f32x4 hv2 = lhp[128 + lane];
    f32x4 hv3 = lhp[192 + lane];

    // 4 gate-row dots vs reg-held weights
    float a0, a1, a2, a3;
    {
      float a;
      a = 0.0f;
      a = fmaf(W0.x, hv0.x, a); a = fmaf(W0.y, hv0.y, a); a = fmaf(W0.z, hv0.z, a); a = fmaf(W0.w, hv0.w, a);
      a = fmaf(W1.x, hv1.x, a); a = fmaf(W1.y, hv1.y, a); a = fmaf(W1.z, hv1.z, a); a = fmaf(W1.w, hv1.w, a);
      a = fmaf(W2.x, hv2.x, a); a = fmaf(W2.y, hv2.y, a); a = fmaf(W2.z, hv2.z, a); a = fmaf(W2.w, hv2.w, a);
      a = fmaf(W3.x, hv3.x, a); a = fmaf(W3.y, hv3.y, a); a = fmaf(W3.z, hv3.z, a); a = fmaf(W3.w, hv3.w, a);
      a0 = a;
      a = 0.0f;
      a = fmaf(W4.x, hv0.x, a); a = fmaf(W4.y, hv0.y, a); a = fmaf(W4.z, hv0.z, a); a = fmaf(W4.w, hv0.w, a);
      a = fmaf(W5.x, hv1.x, a); a = fmaf(W5.y, hv1.y, a); a = fmaf(W5.z, hv1.z, a); a = fmaf(W5.w, hv1.w, a);
      a = fmaf(W6.x, hv2.x, a); a = fmaf(W6.y, hv2.y, a); a = fmaf(W6.z, hv2.z, a); a = fmaf(W6.w, hv2.w, a);
      a = fmaf(W7.x, hv3.x, a); a = fmaf(W7.y, hv3.y, a); a = fmaf(W7.z, hv3.z, a); a = fmaf(W7.w, hv3.w, a);
      a1 = a;
      a = 0.0f;
      a = fmaf(W8.x,  hv0.x, a); a = fmaf(W8.y,  hv0.y, a); a = fmaf(W8.z,  hv0.z, a); a = fmaf(W8.w,  hv0.w, a);
      a = fmaf(W9.x,  hv1.x, a); a = fmaf(W9.y,  hv1.y, a); a = fmaf(W9.z,  hv1.z, a); a = fmaf(W9.w,  hv1.w, a);
      a = fmaf(W10.x, hv2.x, a); a = fmaf(W10.y, hv2.y, a); a = fmaf(W10.z, hv2.z, a); a = fmaf(W10.w, hv2.w, a);
      a = fmaf(W11.x, hv3.x, a); a = fmaf(W11.y, hv3.y, a); a = fmaf(W11.z, hv3.z, a); a = fmaf(W11.w, hv3.w, a);
      a2 = a;
      a = 0.0f;
      a = fmaf(W12.x, hv0.x, a); a = fmaf(W12.y, hv0.y, a); a = fmaf(W12.z, hv0.z, a); a = fmaf(W12.w, hv0.w, a);
      a = fmaf(W13.x, hv1.x, a); a = fmaf(W13.y, hv1.y, a); a = fmaf(W13.z, hv1.z, a); a = fmaf(W13.w, hv1.w, a);
      a = fmaf(W14.x, hv2.x, a); a = fmaf(W14.y, hv2.y, a); a = fmaf(W14.z, hv2.z, a); a = fmaf(W14.w, hv2.w, a);
      a = fmaf(W15.x, hv3.x, a); a = fmaf(W15.y, hv3.y, a); a = fmaf(W15.z, hv3.z, a); a = fmaf(W15.w, hv3.w, a);
      a3 = a;
    }

    // Halving reduce: 3 shuffles land gate (lane&3) in lane; 4 butterflies
    float r0 = halvestep(a0, a1, 1, lane);
    float r1 = halvestep(a2, a3, 1, lane);
    float s  = halvestep(r0, r1, 2, lane);
    s += __shfl_xor(s, 4); s += __shfl_xor(s, 8);
    s += __shfl_xor(s, 16); s += __shfl_xor(s, 32);
    // lane l holds the full pre-activation sum for gate l&3

    const float gv = s + pv;
    // sigmoid for i,f,o; tanh for g via 2*sig(2x)-1
    const bool isg = (g == 2);
    const float sg = sigf(isg ? 2.0f * gv : gv);
    const float act = isg ? fmaf(2.0f, sg, -1.0f) : sg;

    // gather my quad's four gate activations
    const int base = lane & ~3;
    const float si = __shfl(act, base);
    const float sf = __shfl(act, base | 1);
    const float tg = __shfl(act, base | 2);
    const float so = __shfl(act, base | 3);

    c = fmaf(sf, c, si * tg);
    const float s2 = sigf(2.0f * c);
    const float h = so * fmaf(2.0f, s2, -1.0f);   // so * tanh(c)

    if (lane == 0) {
      unsigned long long pk =
          ((unsigned long long)__float_as_uint(h) << 32) | (unsigned)(t + 1);
      __hip_atomic_store(hbuf + (size_t)((t + 1) & 1) * HID + u, pk,
                         __ATOMIC_RELAXED, __HIP_MEMORY_SCOPE_AGENT);
      hall[(size_t)t * HID + u] = h;
    }

    pv = pv_next;
  }
}

// ---------------------------------------------------------------------------
// Workspace layout (bytes):
//   [0, 16K)              : hbuf[2][1024] tagged u64  (memset 0: tag0/h=0)
//   [16K, 16K+33.5MB)     : hall[T][1024]
//   [16K+33.5MB, +134MB)  : pre[T][4096]
// ---------------------------------------------------------------------------
extern "C" void kernel_launch(void* const* d_in, const int* in_sizes, int n_in,
                              void* d_out, int out_size, void* d_ws, size_t ws_size,
                              hipStream_t stream) {
  (void)in_sizes; (void)n_in; (void)out_size; (void)ws_size;

  const float* x     = (const float*)d_in[0];  // [T,1,IN]
  const float* W_w   = (const float*)d_in[1];  // [4096, 2048]
  const float* W_b   = (const float*)d_in[2];  // [4096]
  const float* out_w = (const float*)d_in[3];  // [1024, 1024]
  const float* out_b = (const float*)d_in[4];  // [1024]
  float* out = (float*)d_out;                  // [T,1,1024]

  char* ws = (char*)d_ws;
  unsigned long long* hbuf = (unsigned long long*)ws;
  float* hall = (float*)(ws + 16384);
  float* pre  = (float*)(ws + 16384 + (size_t)T_STEPS * HID * 4);

  hipMemsetAsync(ws, 0, 16384, stream);

  // pre = x @ Wx^T + W_b   (Wx = W_w[:, :1024], row stride 2048)
  gemm_nt<<<dim3(G4 / 64, T_STEPS / 64), 256, 0, stream>>>(
      x, IN_DIM, W_w, IN_DIM + HID, W_b, pre, G4, IN_DIM);

  // sequential recurrence: 256 blocks (1/CU), LDS-resident weights
  lstm_rec<<<NBLK, TPB, 0, stream>>>(W_w, pre, hbuf, hall);

  // y = hall @ out_w^T + out_b
  gemm_nt<<<dim3(OUT_DIM / 64, T_STEPS / 64), 256, 0, stream>>>(
      hall, HID, out_w, OUT_DIM, out_b, out, OUT_DIM, HID);
}